// Round 1
// baseline (1992.483 us; speedup 1.0000x reference)
//
#include <hip/hip_runtime.h>
#include <hip/hip_bf16.h>
#include <cstdint>

// Problem constants: U is 1024x1024, V is 2048x2048, out = Qu @ Qv[:1024,:]  (f32 1024x2048)
#define CI 1024
#define CO 2048
#define NB 256   // WY block size (reflectors per block)

#define BK 16    // GEMM K-tile

// ---------------- utility kernels ----------------

__global__ __launch_bounds__(256) void zero_f32(float* __restrict__ p, int n) {
    int i = blockIdx.x * 256 + threadIdx.x;
    if (i < n) p[i] = 0.0f;
}

// column sum-of-squares with per-block partial + atomicAdd
__global__ __launch_bounds__(256) void colnorm2(const float* __restrict__ M, float* __restrict__ n2, int d) {
    int c = blockIdx.x * 256 + threadIdx.x;          // column
    int r0 = blockIdx.y * 64;
    float s = 0.0f;
    for (int r = r0; r < r0 + 64; ++r) {
        float v = M[(size_t)r * d + c];
        s = fmaf(v, v, s);
    }
    atomicAdd(&n2[c], s);
}

__global__ __launch_bounds__(256) void normalize_cols(const float* __restrict__ M, const float* __restrict__ n2,
                                                      float* __restrict__ Mn, int d) {
    int c = blockIdx.x * 256 + threadIdx.x;
    int r = blockIdx.y;
    Mn[(size_t)r * d + c] = M[(size_t)r * d + c] * (1.0f / sqrtf(n2[c]));
}

// W = [I | 0]   (1024 x 2048, row stride 2048)
__global__ __launch_bounds__(256) void init_W(float* __restrict__ W) {
    int c = blockIdx.x * 256 + threadIdx.x;   // 0..2047
    int r = blockIdx.y;                        // 0..1023
    W[(size_t)r * CO + c] = (c == r) ? 1.0f : 0.0f;
}

// ---------------- Gram: S_z = B^T B, B = A[:, z*NB : (z+1)*NB], batched over grid.z ----------------
__global__ __launch_bounds__(256) void gram_nb(const float* __restrict__ A, int d, float* __restrict__ Sall) {
    int c0 = blockIdx.z * NB;
    float* S = Sall + (size_t)blockIdx.z * NB * NB;
    __shared__ float As[BK][64];
    __shared__ float Bs[BK][64];
    int tid = threadIdx.x;
    int i0 = blockIdx.y * 64, j0 = blockIdx.x * 64;
    int tm = (tid / 16) * 4, tn = (tid % 16) * 4;
    int lr = tid / 16;          // 0..15 k-row
    int lc = (tid % 16) * 4;    // 0..60 col
    float acc[4][4] = {};
    for (int r0 = 0; r0 < d; r0 += BK) {
        *(float4*)&As[lr][lc] = *(const float4*)(A + (size_t)(r0 + lr) * d + c0 + i0 + lc);
        *(float4*)&Bs[lr][lc] = *(const float4*)(A + (size_t)(r0 + lr) * d + c0 + j0 + lc);
        __syncthreads();
        #pragma unroll
        for (int k = 0; k < BK; ++k) {
            float a[4], b[4];
            #pragma unroll
            for (int i = 0; i < 4; ++i) a[i] = As[k][tm + i];
            #pragma unroll
            for (int j = 0; j < 4; ++j) b[j] = Bs[k][tn + j];
            #pragma unroll
            for (int i = 0; i < 4; ++i)
                #pragma unroll
                for (int j = 0; j < 4; ++j) acc[i][j] = fmaf(a[i], b[j], acc[i][j]);
        }
        __syncthreads();
    }
    #pragma unroll
    for (int i = 0; i < 4; ++i) {
        float4 v = make_float4(acc[i][0], acc[i][1], acc[i][2], acc[i][3]);
        *(float4*)(S + (size_t)(i0 + tm + i) * NB + j0 + tn) = v;
    }
}

// ---------------- T = R^{-1}, R = 0.5 I + triu(S,1); column-parallel back substitution ----------------
// one wave per column j; grid (NB, nblocks). Only upper triangle of T is written (lower never read).
__global__ __launch_bounds__(64) void trinv(const float* __restrict__ Sall, float* __restrict__ Tall) {
    int j = blockIdx.x;
    const float* S = Sall + (size_t)blockIdx.y * NB * NB;
    float* T = Tall + (size_t)blockIdx.y * NB * NB;
    volatile __shared__ float x[NB];
    int lane = threadIdx.x;  // 0..63
    if (lane == 0) x[j] = 2.0f;
    for (int i = j - 1; i >= 0; --i) {
        float s = 0.0f;
        for (int k = i + 1 + lane; k <= j; k += 64)
            s += S[(size_t)i * NB + k] * x[k];
        #pragma unroll
        for (int off = 32; off > 0; off >>= 1) s += __shfl_down(s, off);
        if (lane == 0) x[i] = -2.0f * s;
    }
    for (int i = lane; i <= j; i += 64)
        T[(size_t)i * NB + j] = x[i];
}

// ---------------- P (Mx256) <- P @ T (256x256 upper-triangular), in place, row-staged ----------------
__global__ __launch_bounds__(256) void rowmul_T(float* __restrict__ P, const float* __restrict__ T) {
    int r = blockIdx.x;
    int c = threadIdx.x;
    __shared__ float row[NB];
    row[c] = P[(size_t)r * NB + c];
    __syncthreads();
    float s = 0.0f;
    for (int k = 0; k <= c; ++k)            // T is upper triangular; lower part is garbage
        s = fmaf(row[k], T[(size_t)k * NB + c], s);
    P[(size_t)r * NB + c] = s;
}

// ---------------- C = A @ B   (A: MxK ldA, B: KxN ldB, C: MxN ldC) ----------------
__global__ __launch_bounds__(256) void gemm_nn(const float* __restrict__ A, int ldA,
                                               const float* __restrict__ B, int ldB,
                                               float* __restrict__ C, int ldC, int K) {
    __shared__ float As[BK][64];
    __shared__ float Bs[BK][64];
    int tid = threadIdx.x;
    int m0 = blockIdx.y * 64, n0 = blockIdx.x * 64;
    int tm = (tid / 16) * 4, tn = (tid % 16) * 4;
    int ar = tid / 4;            // 0..63 row within A-tile
    int ac = (tid % 4) * 4;      // 0,4,8,12 k within tile
    int bkr = tid / 16;          // 0..15 k-row
    int bc = (tid % 16) * 4;     // 0..60 n
    float acc[4][4] = {};
    for (int k0 = 0; k0 < K; k0 += BK) {
        float4 av = *(const float4*)(A + (size_t)(m0 + ar) * ldA + k0 + ac);
        As[ac + 0][ar] = av.x; As[ac + 1][ar] = av.y; As[ac + 2][ar] = av.z; As[ac + 3][ar] = av.w;
        *(float4*)&Bs[bkr][bc] = *(const float4*)(B + (size_t)(k0 + bkr) * ldB + n0 + bc);
        __syncthreads();
        #pragma unroll
        for (int k = 0; k < BK; ++k) {
            float a[4], b[4];
            #pragma unroll
            for (int i = 0; i < 4; ++i) a[i] = As[k][tm + i];
            #pragma unroll
            for (int j = 0; j < 4; ++j) b[j] = Bs[k][tn + j];
            #pragma unroll
            for (int i = 0; i < 4; ++i)
                #pragma unroll
                for (int j = 0; j < 4; ++j) acc[i][j] = fmaf(a[i], b[j], acc[i][j]);
        }
        __syncthreads();
    }
    #pragma unroll
    for (int i = 0; i < 4; ++i) {
        float4 v = make_float4(acc[i][0], acc[i][1], acc[i][2], acc[i][3]);
        *(float4*)(C + (size_t)(m0 + tm + i) * ldC + n0 + tn) = v;
    }
}

// ---------------- C -= A @ B^T  (A: MxK ldA, B: NxK ldB, C: MxN ldC) ----------------
__global__ __launch_bounds__(256) void gemm_nt_sub(const float* __restrict__ A, int ldA,
                                                   const float* __restrict__ B, int ldB,
                                                   float* __restrict__ C, int ldC, int K) {
    __shared__ float As[BK][64];
    __shared__ float Bs[BK][64];
    int tid = threadIdx.x;
    int m0 = blockIdx.y * 64, n0 = blockIdx.x * 64;
    int tm = (tid / 16) * 4, tn = (tid % 16) * 4;
    int ar = tid / 4;
    int ac = (tid % 4) * 4;
    float acc[4][4] = {};
    for (int k0 = 0; k0 < K; k0 += BK) {
        float4 av = *(const float4*)(A + (size_t)(m0 + ar) * ldA + k0 + ac);
        As[ac + 0][ar] = av.x; As[ac + 1][ar] = av.y; As[ac + 2][ar] = av.z; As[ac + 3][ar] = av.w;
        // B^T tile: Bs[k][n] = B[(n0+n)*ldB + k0+k]; thread loads 4 consecutive k from row n
        float4 bv = *(const float4*)(B + (size_t)(n0 + ar) * ldB + k0 + ac);
        Bs[ac + 0][ar] = bv.x; Bs[ac + 1][ar] = bv.y; Bs[ac + 2][ar] = bv.z; Bs[ac + 3][ar] = bv.w;
        __syncthreads();
        #pragma unroll
        for (int k = 0; k < BK; ++k) {
            float a[4], b[4];
            #pragma unroll
            for (int i = 0; i < 4; ++i) a[i] = As[k][tm + i];
            #pragma unroll
            for (int j = 0; j < 4; ++j) b[j] = Bs[k][tn + j];
            #pragma unroll
            for (int i = 0; i < 4; ++i)
                #pragma unroll
                for (int j = 0; j < 4; ++j) acc[i][j] = fmaf(a[i], b[j], acc[i][j]);
        }
        __syncthreads();
    }
    #pragma unroll
    for (int i = 0; i < 4; ++i) {
        float* cp = C + (size_t)(m0 + tm + i) * ldC + n0 + tn;
        float4 old = *(float4*)cp;
        old.x -= acc[i][0]; old.y -= acc[i][1]; old.z -= acc[i][2]; old.w -= acc[i][3];
        *(float4*)cp = old;
    }
}

extern "C" void kernel_launch(void* const* d_in, const int* in_sizes, int n_in,
                              void* d_out, int out_size, void* d_ws, size_t ws_size,
                              hipStream_t stream) {
    const float* U = (const float*)d_in[0];   // 1024x1024
    const float* V = (const float*)d_in[1];   // 2048x2048
    float* W = (float*)d_out;                 // 1024x2048, used as the evolving product

    char* ws = (char*)d_ws;
    float* Un  = (float*)(ws);                          //  4 MB  (1024^2)
    float* Vn  = (float*)(ws + ((size_t)4  << 20));     // 16 MB  (2048^2)
    float* P   = (float*)(ws + ((size_t)20 << 20));     //  1 MB  (1024x256)
    float* Su  = (float*)(ws + ((size_t)21 << 20));     //  1 MB  (4  x 256^2)
    float* Sv  = (float*)(ws + ((size_t)22 << 20));     //  2 MB  (8  x 256^2)
    float* Tu  = (float*)(ws + ((size_t)24 << 20));     //  1 MB
    float* Tv  = (float*)(ws + ((size_t)25 << 20));     //  2 MB
    float* n2u = (float*)(ws + ((size_t)27 << 20));     //  4 KB
    float* n2v = n2u + CI;                              //  8 KB

    // 1) column norms + normalize
    zero_f32<<<dim3((CI + CO + 255) / 256), dim3(256), 0, stream>>>(n2u, CI + CO);
    colnorm2<<<dim3(CI / 256, CI / 64), dim3(256), 0, stream>>>(U, n2u, CI);
    colnorm2<<<dim3(CO / 256, CO / 64), dim3(256), 0, stream>>>(V, n2v, CO);
    normalize_cols<<<dim3(CI / 256, CI), dim3(256), 0, stream>>>(U, n2u, Un, CI);
    normalize_cols<<<dim3(CO / 256, CO), dim3(256), 0, stream>>>(V, n2v, Vn, CO);

    // 2) per-block Gram + triangular T (all blocks in parallel, ahead of the chain)
    gram_nb<<<dim3(NB / 64, NB / 64, CI / NB), dim3(256), 0, stream>>>(Un, CI, Su);
    gram_nb<<<dim3(NB / 64, NB / 64, CO / NB), dim3(256), 0, stream>>>(Vn, CO, Sv);
    trinv<<<dim3(NB, CI / NB), dim3(64), 0, stream>>>(Su, Tu);
    trinv<<<dim3(NB, CO / NB), dim3(64), 0, stream>>>(Sv, Tv);

    // 3) W = [I | 0]
    init_W<<<dim3(CO / 256, CI), dim3(256), 0, stream>>>(W);

    // 4) U-phase: W[:, :1024] <- W[:, :1024] (I - B T B^T), blocks in order
    for (int ib = 0; ib < CI / NB; ++ib) {
        const float* B = Un + ib * NB;
        gemm_nn<<<dim3(NB / 64, CI / 64), dim3(256), 0, stream>>>(W, CO, B, CI, P, NB, CI);
        rowmul_T<<<dim3(CI), dim3(NB), 0, stream>>>(P, Tu + (size_t)ib * NB * NB);
        gemm_nt_sub<<<dim3(CI / 64, CI / 64), dim3(256), 0, stream>>>(P, NB, B, CI, W, CO, NB);
    }
    // 5) V-phase: W <- W (I - B T B^T), full 2048 columns
    for (int ib = 0; ib < CO / NB; ++ib) {
        const float* B = Vn + ib * NB;
        gemm_nn<<<dim3(NB / 64, CI / 64), dim3(256), 0, stream>>>(W, CO, B, CO, P, NB, CO);
        rowmul_T<<<dim3(CI), dim3(NB), 0, stream>>>(P, Tv + (size_t)ib * NB * NB);
        gemm_nt_sub<<<dim3(CO / 64, CI / 64), dim3(256), 0, stream>>>(P, NB, B, CO, W, CO, NB);
    }
}

// Round 2
// 1792.943 us; speedup vs baseline: 1.1113x; 1.1113x over previous
//
#include <hip/hip_runtime.h>
#include <hip/hip_bf16.h>
#include <cstdint>

// Problem constants: U is 1024x1024, V is 2048x2048, out = Qu @ Qv[:1024,:]  (f32 1024x2048)
#define CI 1024
#define CO 2048
#define NB 256   // WY block size (reflectors per block)
#define BK 16    // GEMM K-tile

// ---------------- utility kernels ----------------

__global__ __launch_bounds__(256) void zero_f32(float* __restrict__ p, int n) {
    int i = blockIdx.x * 256 + threadIdx.x;
    if (i < n) p[i] = 0.0f;
}

__global__ __launch_bounds__(256) void colnorm2(const float* __restrict__ M, float* __restrict__ n2, int d) {
    int c = blockIdx.x * 256 + threadIdx.x;
    int r0 = blockIdx.y * 64;
    float s = 0.0f;
    for (int r = r0; r < r0 + 64; ++r) {
        float v = M[(size_t)r * d + c];
        s = fmaf(v, v, s);
    }
    atomicAdd(&n2[c], s);
}

__global__ __launch_bounds__(256) void normalize_cols(const float* __restrict__ M, const float* __restrict__ n2,
                                                      float* __restrict__ Mn, int d) {
    int c = blockIdx.x * 256 + threadIdx.x;
    int r = blockIdx.y;
    Mn[(size_t)r * d + c] = M[(size_t)r * d + c] * (1.0f / sqrtf(n2[c]));
}

// W = [I | 0]   (1024 x 2048)
__global__ __launch_bounds__(256) void init_W(float* __restrict__ W) {
    int c = blockIdx.x * 256 + threadIdx.x;
    int r = blockIdx.y;
    W[(size_t)r * CO + c] = (c == r) ? 1.0f : 0.0f;
}

// ---------------- Gram: S_z = B^T B (full, symmetric), 128 threads, 8x4 acc ----------------
__global__ __launch_bounds__(128) void gram128(const float* __restrict__ A, int d, float* __restrict__ Sall) {
    int c0 = blockIdx.z * NB;
    float* S = Sall + (size_t)blockIdx.z * NB * NB;
    __shared__ float As[BK][64];
    __shared__ float Bs[BK][64];
    int tid = threadIdx.x;
    int i0 = blockIdx.y * 64, j0 = blockIdx.x * 64;
    int tm = (tid >> 4) * 8, tn = (tid & 15) * 4;
    int sk = tid >> 4;            // 0..7 k-row for direct stage
    int sc = (tid & 15) * 4;      // column within tile
    float acc[8][4] = {};
    for (int k0 = 0; k0 < d; k0 += BK) {
        #pragma unroll
        for (int p = 0; p < 2; ++p) {
            int kk = sk + p * 8;
            *(float4*)&As[kk][sc] = *(const float4*)(A + (size_t)(k0 + kk) * d + c0 + i0 + sc);
            *(float4*)&Bs[kk][sc] = *(const float4*)(A + (size_t)(k0 + kk) * d + c0 + j0 + sc);
        }
        __syncthreads();
        #pragma unroll
        for (int k = 0; k < BK; ++k) {
            float4 alo = *(const float4*)&As[k][tm];
            float4 ahi = *(const float4*)&As[k][tm + 4];
            float4 bv  = *(const float4*)&Bs[k][tn];
            float a[8] = {alo.x, alo.y, alo.z, alo.w, ahi.x, ahi.y, ahi.z, ahi.w};
            float b[4] = {bv.x, bv.y, bv.z, bv.w};
            #pragma unroll
            for (int i = 0; i < 8; ++i)
                #pragma unroll
                for (int j = 0; j < 4; ++j) acc[i][j] = fmaf(a[i], b[j], acc[i][j]);
        }
        __syncthreads();
    }
    #pragma unroll
    for (int i = 0; i < 8; ++i) {
        float4 v = make_float4(acc[i][0], acc[i][1], acc[i][2], acc[i][3]);
        *(float4*)(S + (size_t)(i0 + tm + i) * NB + j0 + tn) = v;
    }
}

// ---------------- T = (0.5 I + triu(S,1))^{-1}, right-looking, register-resident ----------------
// One wave per (column j, matrix). Uses S symmetric: S[i][k] == S[k][i] -> row-k reads are coalesced.
// Writes the FULL 256x256 T (zeros below diagonal) so P@T can be a dense GEMM.
__global__ __launch_bounds__(64) void trinv_rl(const float* __restrict__ Sall, float* __restrict__ Tall) {
    int j = blockIdx.x;
    const float* S = Sall + (size_t)blockIdx.y * NB * NB;
    float* T = Tall + (size_t)blockIdx.y * NB * NB;
    int l = threadIdx.x;
    float x0 = 0, x1 = 0, x2 = 0, x3 = 0;   // x[l], x[64+l], x[128+l], x[192+l]
    float a0 = 0, a1 = 0, a2 = 0, a3 = 0;   // running partial sums
    int jq = j >> 6, jr = j & 63;
    if (l == jr) {
        if (jq == 0) x0 = 2.0f; else if (jq == 1) x1 = 2.0f; else if (jq == 2) x2 = 2.0f; else x3 = 2.0f;
    }
    // prefetch row j
    float s0 = 0, s1 = 0, s2 = 0, s3 = 0;
    if (j >= 1) {
        const float* Sr = S + (size_t)j * NB;
        s0 = Sr[l]; s1 = Sr[l + 64]; s2 = Sr[l + 128]; s3 = Sr[l + 192];
    }
    for (int k = j; k >= 1; --k) {
        int kq = k >> 6, kr = k & 63;
        float xk;
        if      (kq == 0) xk = __shfl(x0, kr);
        else if (kq == 1) xk = __shfl(x1, kr);
        else if (kq == 2) xk = __shfl(x2, kr);
        else              xk = __shfl(x3, kr);
        float c0 = s0, c1 = s1, c2 = s2, c3 = s3;
        if (k > 1) {  // prefetch next row (independent of the dependency chain)
            const float* Sn = S + (size_t)(k - 1) * NB;
            s0 = Sn[l]; s1 = Sn[l + 64]; s2 = Sn[l + 128]; s3 = Sn[l + 192];
        }
        a0 = fmaf(c0, xk, a0);
        a1 = fmaf(c1, xk, a1);
        a2 = fmaf(c2, xk, a2);
        a3 = fmaf(c3, xk, a3);
        int i = k - 1, iq = i >> 6, ir = i & 63;
        if (l == ir) {
            if      (iq == 0) x0 = -2.0f * a0;
            else if (iq == 1) x1 = -2.0f * a1;
            else if (iq == 2) x2 = -2.0f * a2;
            else              x3 = -2.0f * a3;
        }
    }
    T[(size_t)(l      ) * NB + j] = x0;
    T[(size_t)(l +  64) * NB + j] = x1;
    T[(size_t)(l + 128) * NB + j] = x2;
    T[(size_t)(l + 192) * NB + j] = x3;
}

// ---------------- C (+)= A @ B   64x64 tile, 128 threads, 8x4 acc, optional split-K atomic ----------------
template<bool ATOMIC>
__global__ __launch_bounds__(128) void gemm128_nn(const float* __restrict__ A, int ldA,
                                                  const float* __restrict__ B, int ldB,
                                                  float* __restrict__ C, int ldC, int kchunk) {
    int m0 = blockIdx.y * 64, n0 = blockIdx.x * 64;
    int kb = blockIdx.z * kchunk, ke = kb + kchunk;
    __shared__ float As[BK][64];   // [k][m] so inner reads are b128 broadcasts
    __shared__ float Bs[BK][64];
    int tid = threadIdx.x;
    int tm = (tid >> 4) * 8, tn = (tid & 15) * 4;
    int ar = tid >> 2;            // 0..31 (A stage: row within tile)
    int ac = (tid & 3) * 4;       // k within tile
    int bk = tid >> 4;            // 0..7 (B stage: k row)
    int bn = (tid & 15) * 4;
    float acc[8][4] = {};
    for (int k0 = kb; k0 < ke; k0 += BK) {
        #pragma unroll
        for (int p = 0; p < 2; ++p) {
            int r = ar + p * 32;
            float4 av = *(const float4*)(A + (size_t)(m0 + r) * ldA + k0 + ac);
            As[ac + 0][r] = av.x; As[ac + 1][r] = av.y; As[ac + 2][r] = av.z; As[ac + 3][r] = av.w;
        }
        #pragma unroll
        for (int p = 0; p < 2; ++p) {
            int kk = bk + p * 8;
            *(float4*)&Bs[kk][bn] = *(const float4*)(B + (size_t)(k0 + kk) * ldB + n0 + bn);
        }
        __syncthreads();
        #pragma unroll
        for (int k = 0; k < BK; ++k) {
            float4 alo = *(const float4*)&As[k][tm];
            float4 ahi = *(const float4*)&As[k][tm + 4];
            float4 bv  = *(const float4*)&Bs[k][tn];
            float a[8] = {alo.x, alo.y, alo.z, alo.w, ahi.x, ahi.y, ahi.z, ahi.w};
            float b[4] = {bv.x, bv.y, bv.z, bv.w};
            #pragma unroll
            for (int i = 0; i < 8; ++i)
                #pragma unroll
                for (int j = 0; j < 4; ++j) acc[i][j] = fmaf(a[i], b[j], acc[i][j]);
        }
        __syncthreads();
    }
    if (ATOMIC) {
        #pragma unroll
        for (int i = 0; i < 8; ++i)
            #pragma unroll
            for (int j = 0; j < 4; ++j)
                atomicAdd(C + (size_t)(m0 + tm + i) * ldC + n0 + tn + j, acc[i][j]);
    } else {
        #pragma unroll
        for (int i = 0; i < 8; ++i) {
            float4 v = make_float4(acc[i][0], acc[i][1], acc[i][2], acc[i][3]);
            *(float4*)(C + (size_t)(m0 + tm + i) * ldC + n0 + tn) = v;
        }
    }
}

// ---------------- C -= A @ B^T   (A: MxK, B: NxK), K = NB, 64x64 tile, 128 threads ----------------
__global__ __launch_bounds__(128) void gemm128_nt_sub(const float* __restrict__ A, int ldA,
                                                      const float* __restrict__ B, int ldB,
                                                      float* __restrict__ C, int ldC) {
    int m0 = blockIdx.y * 64, n0 = blockIdx.x * 64;
    __shared__ float As[BK][64];
    __shared__ float Bs[BK][64];
    int tid = threadIdx.x;
    int tm = (tid >> 4) * 8, tn = (tid & 15) * 4;
    int ar = tid >> 2;
    int ac = (tid & 3) * 4;
    float acc[8][4] = {};
    for (int k0 = 0; k0 < NB; k0 += BK) {
        #pragma unroll
        for (int p = 0; p < 2; ++p) {
            int r = ar + p * 32;
            float4 av = *(const float4*)(A + (size_t)(m0 + r) * ldA + k0 + ac);
            As[ac + 0][r] = av.x; As[ac + 1][r] = av.y; As[ac + 2][r] = av.z; As[ac + 3][r] = av.w;
            float4 bv = *(const float4*)(B + (size_t)(n0 + r) * ldB + k0 + ac);
            Bs[ac + 0][r] = bv.x; Bs[ac + 1][r] = bv.y; Bs[ac + 2][r] = bv.z; Bs[ac + 3][r] = bv.w;
        }
        __syncthreads();
        #pragma unroll
        for (int k = 0; k < BK; ++k) {
            float4 alo = *(const float4*)&As[k][tm];
            float4 ahi = *(const float4*)&As[k][tm + 4];
            float4 bv  = *(const float4*)&Bs[k][tn];
            float a[8] = {alo.x, alo.y, alo.z, alo.w, ahi.x, ahi.y, ahi.z, ahi.w};
            float b[4] = {bv.x, bv.y, bv.z, bv.w};
            #pragma unroll
            for (int i = 0; i < 8; ++i)
                #pragma unroll
                for (int j = 0; j < 4; ++j) acc[i][j] = fmaf(a[i], b[j], acc[i][j]);
        }
        __syncthreads();
    }
    #pragma unroll
    for (int i = 0; i < 8; ++i) {
        float* cp = C + (size_t)(m0 + tm + i) * ldC + n0 + tn;
        float4 old = *(float4*)cp;
        old.x -= acc[i][0]; old.y -= acc[i][1]; old.z -= acc[i][2]; old.w -= acc[i][3];
        *(float4*)cp = old;
    }
}

extern "C" void kernel_launch(void* const* d_in, const int* in_sizes, int n_in,
                              void* d_out, int out_size, void* d_ws, size_t ws_size,
                              hipStream_t stream) {
    const float* U = (const float*)d_in[0];   // 1024x1024
    const float* V = (const float*)d_in[1];   // 2048x2048
    float* W = (float*)d_out;                 // 1024x2048, the evolving product

    char* ws = (char*)d_ws;
    float* Un  = (float*)(ws);                          //  4 MB
    float* Vn  = (float*)(ws + ((size_t)4  << 20));     // 16 MB
    float* P   = (float*)(ws + ((size_t)20 << 20));     //  1 MB (1024x256)
    float* P0  = (float*)(ws + ((size_t)21 << 20));     //  1 MB (1024x256, split-K target)
    float* S   = (float*)(ws + ((size_t)22 << 20));     //  3 MB (12 x 256^2), U blocks then V blocks
    float* T   = (float*)(ws + ((size_t)25 << 20));     //  3 MB
    float* n2u = (float*)(ws + ((size_t)28 << 20));     //  4 KB
    float* n2v = n2u + CI;

    float* Su = S;               float* Sv = S + (size_t)4 * NB * NB;
    float* Tu = T;               float* Tv = T + (size_t)4 * NB * NB;

    // 1) column norms + normalize
    zero_f32<<<dim3((CI + CO + 255) / 256), dim3(256), 0, stream>>>(n2u, CI + CO);
    colnorm2<<<dim3(CI / 256, CI / 64), dim3(256), 0, stream>>>(U, n2u, CI);
    colnorm2<<<dim3(CO / 256, CO / 64), dim3(256), 0, stream>>>(V, n2v, CO);
    normalize_cols<<<dim3(CI / 256, CI), dim3(256), 0, stream>>>(U, n2u, Un, CI);
    normalize_cols<<<dim3(CO / 256, CO), dim3(256), 0, stream>>>(V, n2v, Vn, CO);

    // 2) per-block Gram + T (all 12 blocks in one trinv dispatch; S/T laid out contiguously)
    gram128<<<dim3(NB / 64, NB / 64, CI / NB), dim3(128), 0, stream>>>(Un, CI, Su);
    gram128<<<dim3(NB / 64, NB / 64, CO / NB), dim3(128), 0, stream>>>(Vn, CO, Sv);
    trinv_rl<<<dim3(NB, (CI + CO) / NB), dim3(64), 0, stream>>>(S, T);

    // 3) W = [I | 0]
    init_W<<<dim3(CO / 256, CI), dim3(256), 0, stream>>>(W);

    // 4) U-phase: W[:, :1024] <- W[:, :1024] (I - B T B^T)
    for (int ib = 0; ib < CI / NB; ++ib) {
        const float* B = Un + ib * NB;
        hipMemsetAsync(P0, 0, (size_t)CI * NB * 4, stream);
        gemm128_nn<true><<<dim3(NB / 64, CI / 64, 8), dim3(128), 0, stream>>>(W, CO, B, CI, P0, NB, CI / 8);
        gemm128_nn<false><<<dim3(NB / 64, CI / 64, 1), dim3(128), 0, stream>>>(P0, NB, Tu + (size_t)ib * NB * NB, NB, P, NB, NB);
        gemm128_nt_sub<<<dim3(CI / 64, CI / 64), dim3(128), 0, stream>>>(P, NB, B, CI, W, CO);
    }
    // 5) V-phase: W <- W (I - B T B^T), full 2048 columns
    for (int ib = 0; ib < CO / NB; ++ib) {
        const float* B = Vn + ib * NB;
        hipMemsetAsync(P0, 0, (size_t)CI * NB * 4, stream);
        gemm128_nn<true><<<dim3(NB / 64, CI / 64, 8), dim3(128), 0, stream>>>(W, CO, B, CO, P0, NB, CO / 8);
        gemm128_nn<false><<<dim3(NB / 64, CI / 64, 1), dim3(128), 0, stream>>>(P0, NB, Tv + (size_t)ib * NB * NB, NB, P, NB, NB);
        gemm128_nt_sub<<<dim3(CO / 64, CI / 64), dim3(128), 0, stream>>>(P, NB, B, CO, W, CO);
    }
}

// Round 3
// 1324.568 us; speedup vs baseline: 1.5043x; 1.3536x over previous
//
#include <hip/hip_runtime.h>
#include <hip/hip_bf16.h>
#include <cstdint>

// U: 1024x1024, V: 2048x2048, out = Qu @ Qv[:1024,:]  (f32 1024x2048)
#define CI 1024
#define CO 2048
#define NB 256   // WY block size
#define BK 16    // GEMM K-tile

// ---------------- utility ----------------

__global__ __launch_bounds__(256) void colnorm2(const float* __restrict__ M, float* __restrict__ n2, int d) {
    int c = blockIdx.x * 256 + threadIdx.x;
    int r0 = blockIdx.y * 64;
    float s = 0.0f;
    for (int r = r0; r < r0 + 64; ++r) {
        float v = M[(size_t)r * d + c];
        s = fmaf(v, v, s);
    }
    atomicAdd(&n2[c], s);
}

// W = [I | 0]   (1024 x 2048)
__global__ __launch_bounds__(256) void init_W(float* __restrict__ W) {
    int c = blockIdx.x * 256 + threadIdx.x;
    int r = blockIdx.y;
    W[(size_t)r * CO + c] = (c == r) ? 1.0f : 0.0f;
}

// P0 = U[:, 0:256]  (first U-block shortcut: W = [I|0] so W@B = B)
__global__ __launch_bounds__(256) void copy_ublock0(const float* __restrict__ U, float* __restrict__ P0) {
    int c = threadIdx.x;
    int r = blockIdx.x;
    P0[(size_t)r * NB + c] = U[(size_t)r * CI + c];
}

// ---------------- Gram (raw): S_zb += A[:,zb*NB:...]^T A[...], split-K, atomic ----------------
__global__ __launch_bounds__(128) void gram_splitk(const float* __restrict__ A, int d, int split,
                                                   float* __restrict__ Sall) {
    int zb = blockIdx.z / split, ks = blockIdx.z % split;
    int chunk = d / split;
    int c0 = zb * NB;
    float* S = Sall + (size_t)zb * NB * NB;
    __shared__ float As[BK][64];
    __shared__ float Bs[BK][64];
    int tid = threadIdx.x;
    int i0 = blockIdx.y * 64, j0 = blockIdx.x * 64;
    int tm = (tid >> 4) * 8, tn = (tid & 15) * 4;
    int sk = tid >> 4;
    int sc = (tid & 15) * 4;
    float acc[8][4] = {};
    int kb = ks * chunk, ke = kb + chunk;
    for (int k0 = kb; k0 < ke; k0 += BK) {
        #pragma unroll
        for (int p = 0; p < 2; ++p) {
            int kk = sk + p * 8;
            *(float4*)&As[kk][sc] = *(const float4*)(A + (size_t)(k0 + kk) * d + c0 + i0 + sc);
            *(float4*)&Bs[kk][sc] = *(const float4*)(A + (size_t)(k0 + kk) * d + c0 + j0 + sc);
        }
        __syncthreads();
        #pragma unroll
        for (int k = 0; k < BK; ++k) {
            float4 alo = *(const float4*)&As[k][tm];
            float4 ahi = *(const float4*)&As[k][tm + 4];
            float4 bv  = *(const float4*)&Bs[k][tn];
            float a[8] = {alo.x, alo.y, alo.z, alo.w, ahi.x, ahi.y, ahi.z, ahi.w};
            float b[4] = {bv.x, bv.y, bv.z, bv.w};
            #pragma unroll
            for (int i = 0; i < 8; ++i)
                #pragma unroll
                for (int j = 0; j < 4; ++j) acc[i][j] = fmaf(a[i], b[j], acc[i][j]);
        }
        __syncthreads();
    }
    #pragma unroll
    for (int i = 0; i < 8; ++i)
        #pragma unroll
        for (int j = 0; j < 4; ++j)
            atomicAdd(S + (size_t)(i0 + tm + i) * NB + j0 + tn + j, acc[i][j]);
}

// ---------------- M = D T D with T = (0.5 I + triu(D S D, 1))^{-1}; register-resident ----------------
// y_k = invn_k * x_k recurrence over the RAW Gram S; writes full 256x256 M (zeros below diag).
__global__ __launch_bounds__(64) void trinv_scaled(const float* __restrict__ Sall, float* __restrict__ Mall,
                                                   const float* __restrict__ n2u, const float* __restrict__ n2v) {
    int j = blockIdx.x;
    int b = blockIdx.y;
    const float* S = Sall + (size_t)b * NB * NB;
    float* M = Mall + (size_t)b * NB * NB;
    const float* n2 = (b < 4) ? (n2u + b * NB) : (n2v + (size_t)(b - 4) * NB);
    int l = threadIdx.x;
    float in0 = 1.0f / sqrtf(n2[l]);
    float in1 = 1.0f / sqrtf(n2[l + 64]);
    float in2 = 1.0f / sqrtf(n2[l + 128]);
    float in3 = 1.0f / sqrtf(n2[l + 192]);
    float invnj = 1.0f / sqrtf(n2[j]);
    float i20 = in0 * in0, i21 = in1 * in1, i22 = in2 * in2, i23 = in3 * in3;
    float x0 = 0, x1 = 0, x2 = 0, x3 = 0;   // y[l], y[64+l], y[128+l], y[192+l]
    float a0 = 0, a1 = 0, a2 = 0, a3 = 0;
    int jq = j >> 6, jr = j & 63;
    if (l == jr) {
        float yj = 2.0f * invnj;
        if (jq == 0) x0 = yj; else if (jq == 1) x1 = yj; else if (jq == 2) x2 = yj; else x3 = yj;
    }
    float s0 = 0, s1 = 0, s2 = 0, s3 = 0;
    if (j >= 1) {
        const float* Sr = S + (size_t)j * NB;
        s0 = Sr[l]; s1 = Sr[l + 64]; s2 = Sr[l + 128]; s3 = Sr[l + 192];
    }
    for (int k = j; k >= 1; --k) {
        int kq = k >> 6, kr = k & 63;
        float yk;
        if      (kq == 0) yk = __shfl(x0, kr);
        else if (kq == 1) yk = __shfl(x1, kr);
        else if (kq == 2) yk = __shfl(x2, kr);
        else              yk = __shfl(x3, kr);
        float c0 = s0, c1 = s1, c2 = s2, c3 = s3;
        if (k > 1) {
            const float* Sn = S + (size_t)(k - 1) * NB;
            s0 = Sn[l]; s1 = Sn[l + 64]; s2 = Sn[l + 128]; s3 = Sn[l + 192];
        }
        a0 = fmaf(c0, yk, a0);
        a1 = fmaf(c1, yk, a1);
        a2 = fmaf(c2, yk, a2);
        a3 = fmaf(c3, yk, a3);
        int i = k - 1, iq = i >> 6, ir = i & 63;
        if (l == ir) {
            if      (iq == 0) x0 = -2.0f * i20 * a0;
            else if (iq == 1) x1 = -2.0f * i21 * a1;
            else if (iq == 2) x2 = -2.0f * i22 * a2;
            else              x3 = -2.0f * i23 * a3;
        }
    }
    M[(size_t)(l      ) * NB + j] = x0 * invnj;
    M[(size_t)(l +  64) * NB + j] = x1 * invnj;
    M[(size_t)(l + 128) * NB + j] = x2 * invnj;
    M[(size_t)(l + 192) * NB + j] = x3 * invnj;
}

// ---------------- TB_z = M_z @ B_z^T  (nt, K=NB, batched over z) ----------------
// C(m,n) = sum_k A(m,k) * Bsrc(n, c0z + k);  A: 256x256, Bsrc: d x d, C: 256 x d
__global__ __launch_bounds__(128) void gemm128_nt_batch(const float* __restrict__ Aall,
                                                        const float* __restrict__ Bsrc, int d,
                                                        float* __restrict__ Call) {
    int z = blockIdx.z;
    const float* A = Aall + (size_t)z * NB * NB;
    const float* B = Bsrc + (size_t)z * NB;        // column offset c0 = z*NB
    float* C = Call + (size_t)z * NB * d;
    int m0 = blockIdx.y * 64, n0 = blockIdx.x * 64;
    __shared__ float As[BK][64];
    __shared__ float Bs[BK][64];
    int tid = threadIdx.x;
    int tm = (tid >> 4) * 8, tn = (tid & 15) * 4;
    int ar = tid >> 2;
    int ac = (tid & 3) * 4;
    float acc[8][4] = {};
    for (int k0 = 0; k0 < NB; k0 += BK) {
        #pragma unroll
        for (int p = 0; p < 2; ++p) {
            int r = ar + p * 32;
            float4 av = *(const float4*)(A + (size_t)(m0 + r) * NB + k0 + ac);
            As[ac + 0][r] = av.x; As[ac + 1][r] = av.y; As[ac + 2][r] = av.z; As[ac + 3][r] = av.w;
            float4 bv = *(const float4*)(B + (size_t)(n0 + r) * d + k0 + ac);
            Bs[ac + 0][r] = bv.x; Bs[ac + 1][r] = bv.y; Bs[ac + 2][r] = bv.z; Bs[ac + 3][r] = bv.w;
        }
        __syncthreads();
        #pragma unroll
        for (int k = 0; k < BK; ++k) {
            float4 alo = *(const float4*)&As[k][tm];
            float4 ahi = *(const float4*)&As[k][tm + 4];
            float4 bv  = *(const float4*)&Bs[k][tn];
            float a[8] = {alo.x, alo.y, alo.z, alo.w, ahi.x, ahi.y, ahi.z, ahi.w};
            float b[4] = {bv.x, bv.y, bv.z, bv.w};
            #pragma unroll
            for (int i = 0; i < 8; ++i)
                #pragma unroll
                for (int j = 0; j < 4; ++j) acc[i][j] = fmaf(a[i], b[j], acc[i][j]);
        }
        __syncthreads();
    }
    #pragma unroll
    for (int i = 0; i < 8; ++i) {
        float4 v = make_float4(acc[i][0], acc[i][1], acc[i][2], acc[i][3]);
        *(float4*)(C + (size_t)(m0 + tm + i) * d + n0 + tn) = v;
    }
}

// ---------------- C (op)= A @ B   64x64 tile, 128 threads, 8x4 acc ----------------
// CMODE: 0 = store, 1 = atomicAdd (split-K), 2 = subtract (rmw)
template<int CMODE>
__global__ __launch_bounds__(128) void gemm128_nn(const float* __restrict__ A, int ldA,
                                                  const float* __restrict__ B, int ldB,
                                                  float* __restrict__ C, int ldC, int kchunk) {
    int m0 = blockIdx.y * 64, n0 = blockIdx.x * 64;
    int kb = blockIdx.z * kchunk, ke = kb + kchunk;
    __shared__ float As[BK][64];
    __shared__ float Bs[BK][64];
    int tid = threadIdx.x;
    int tm = (tid >> 4) * 8, tn = (tid & 15) * 4;
    int ar = tid >> 2;
    int ac = (tid & 3) * 4;
    int bk = tid >> 4;
    int bn = (tid & 15) * 4;
    float acc[8][4] = {};
    for (int k0 = kb; k0 < ke; k0 += BK) {
        #pragma unroll
        for (int p = 0; p < 2; ++p) {
            int r = ar + p * 32;
            float4 av = *(const float4*)(A + (size_t)(m0 + r) * ldA + k0 + ac);
            As[ac + 0][r] = av.x; As[ac + 1][r] = av.y; As[ac + 2][r] = av.z; As[ac + 3][r] = av.w;
        }
        #pragma unroll
        for (int p = 0; p < 2; ++p) {
            int kk = bk + p * 8;
            *(float4*)&Bs[kk][bn] = *(const float4*)(B + (size_t)(k0 + kk) * ldB + n0 + bn);
        }
        __syncthreads();
        #pragma unroll
        for (int k = 0; k < BK; ++k) {
            float4 alo = *(const float4*)&As[k][tm];
            float4 ahi = *(const float4*)&As[k][tm + 4];
            float4 bv  = *(const float4*)&Bs[k][tn];
            float a[8] = {alo.x, alo.y, alo.z, alo.w, ahi.x, ahi.y, ahi.z, ahi.w};
            float b[4] = {bv.x, bv.y, bv.z, bv.w};
            #pragma unroll
            for (int i = 0; i < 8; ++i)
                #pragma unroll
                for (int j = 0; j < 4; ++j) acc[i][j] = fmaf(a[i], b[j], acc[i][j]);
        }
        __syncthreads();
    }
    if (CMODE == 1) {
        #pragma unroll
        for (int i = 0; i < 8; ++i)
            #pragma unroll
            for (int j = 0; j < 4; ++j)
                atomicAdd(C + (size_t)(m0 + tm + i) * ldC + n0 + tn + j, acc[i][j]);
    } else if (CMODE == 2) {
        #pragma unroll
        for (int i = 0; i < 8; ++i) {
            float* cp = C + (size_t)(m0 + tm + i) * ldC + n0 + tn;
            float4 old = *(float4*)cp;
            old.x -= acc[i][0]; old.y -= acc[i][1]; old.z -= acc[i][2]; old.w -= acc[i][3];
            *(float4*)cp = old;
        }
    } else {
        #pragma unroll
        for (int i = 0; i < 8; ++i) {
            float4 v = make_float4(acc[i][0], acc[i][1], acc[i][2], acc[i][3]);
            *(float4*)(C + (size_t)(m0 + tm + i) * ldC + n0 + tn) = v;
        }
    }
}

extern "C" void kernel_launch(void* const* d_in, const int* in_sizes, int n_in,
                              void* d_out, int out_size, void* d_ws, size_t ws_size,
                              hipStream_t stream) {
    const float* U = (const float*)d_in[0];   // 1024x1024
    const float* V = (const float*)d_in[1];   // 2048x2048
    float* W = (float*)d_out;                 // 1024x2048, evolving product

    char* ws = (char*)d_ws;
    float* P0  = (float*)(ws);                          //  1 MB (1024x256)
    float* S   = (float*)(ws + ((size_t)1  << 20));     //  3 MB (12 x 256^2): 4 U then 8 V
    float* M   = (float*)(ws + ((size_t)4  << 20));     //  3 MB (scaled T = D T D)
    float* TBu = (float*)(ws + ((size_t)7  << 20));     //  4 MB (4 x 256x1024)
    float* TBv = (float*)(ws + ((size_t)11 << 20));     // 16 MB (8 x 256x2048)
    float* n2u = (float*)(ws + ((size_t)27 << 20));     //  4 KB
    float* n2v = n2u + CI;                              //  8 KB

    float* Su = S;  float* Sv = S + (size_t)4 * NB * NB;
    float* Mu = M;  float* Mv = M + (size_t)4 * NB * NB;

    // 1) raw column norms (normalization folded into M downstream)
    hipMemsetAsync(n2u, 0, (CI + CO) * sizeof(float), stream);
    hipMemsetAsync(S, 0, (size_t)12 * NB * NB * sizeof(float), stream);
    colnorm2<<<dim3(CI / 256, CI / 64), dim3(256), 0, stream>>>(U, n2u, CI);
    colnorm2<<<dim3(CO / 256, CO / 64), dim3(256), 0, stream>>>(V, n2v, CO);

    // 2) raw Gram via split-K (chunk 128) + scaled triangular inverse
    gram_splitk<<<dim3(NB / 64, NB / 64, (CI / NB) * 8),  dim3(128), 0, stream>>>(U, CI, 8,  Su);
    gram_splitk<<<dim3(NB / 64, NB / 64, (CO / NB) * 16), dim3(128), 0, stream>>>(V, CO, 16, Sv);
    trinv_scaled<<<dim3(NB, 12), dim3(64), 0, stream>>>(S, M, n2u, n2v);

    // 3) TB_i = M_i @ B_i^T  (all blocks in parallel)
    gemm128_nt_batch<<<dim3(CI / 64, NB / 64, CI / NB), dim3(128), 0, stream>>>(Mu, U, CI, TBu);
    gemm128_nt_batch<<<dim3(CO / 64, NB / 64, CO / NB), dim3(128), 0, stream>>>(Mv, V, CO, TBv);

    // 4) W = [I | 0]
    init_W<<<dim3(CO / 256, CI), dim3(256), 0, stream>>>(W);

    // 5) U-phase: W[:, :1024] <- W[:, :1024] - (W B_i)(TB_i)
    for (int ib = 0; ib < CI / NB; ++ib) {
        if (ib == 0) {
            copy_ublock0<<<dim3(CI), dim3(256), 0, stream>>>(U, P0);
        } else {
            hipMemsetAsync(P0, 0, (size_t)CI * NB * sizeof(float), stream);
            gemm128_nn<1><<<dim3(NB / 64, CI / 64, 8), dim3(128), 0, stream>>>(
                W, CO, U + ib * NB, CI, P0, NB, CI / 8);
        }
        gemm128_nn<2><<<dim3(CI / 64, CI / 64, 1), dim3(128), 0, stream>>>(
            P0, NB, TBu + (size_t)ib * NB * CI, CI, W, CO, NB);
    }
    // 6) V-phase: W <- W - (W B_i)(TB_i), full 2048 columns
    for (int ib = 0; ib < CO / NB; ++ib) {
        hipMemsetAsync(P0, 0, (size_t)CI * NB * sizeof(float), stream);
        gemm128_nn<1><<<dim3(NB / 64, CI / 64, 8), dim3(128), 0, stream>>>(
            W, CO, V + ib * NB, CO, P0, NB, CO / 8);
        gemm128_nn<2><<<dim3(CO / 64, CI / 64, 1), dim3(128), 0, stream>>>(
            P0, NB, TBv + (size_t)ib * NB * CO, CO, W, CO, NB);
    }
}

// Round 4
// 1324.510 us; speedup vs baseline: 1.5043x; 1.0000x over previous
//
#include <hip/hip_runtime.h>
#include <hip/hip_bf16.h>
#include <cstdint>

// U: 1024x1024, V: 2048x2048, out = Qu @ Qv[:1024,:]  (f32 1024x2048)
#define CI 1024
#define CO 2048
#define NB 256   // WY block size
#define BK 16    // GEMM K-tile

// ---------------- utility ----------------

__global__ __launch_bounds__(256) void colnorm2(const float* __restrict__ M, float* __restrict__ n2, int d) {
    int c = blockIdx.x * 256 + threadIdx.x;
    int r0 = blockIdx.y * 64;
    float s = 0.0f;
    for (int r = r0; r < r0 + 64; ++r) {
        float v = M[(size_t)r * d + c];
        s = fmaf(v, v, s);
    }
    atomicAdd(&n2[c], s);
}

// W = [I | 0]   (1024 x 2048)
__global__ __launch_bounds__(256) void init_W(float* __restrict__ W) {
    int c = blockIdx.x * 256 + threadIdx.x;
    int r = blockIdx.y;
    W[(size_t)r * CO + c] = (c == r) ? 1.0f : 0.0f;
}

// ---------------- Gram partials: Spart[z] = A[:,zb]^T A[:,zb] over K-chunk ks ----------------
__global__ __launch_bounds__(128) void gram_part(const float* __restrict__ A, int d, int split,
                                                 float* __restrict__ Spart) {
    int z = blockIdx.z;
    int zb = z / split, ks = z % split;
    int chunk = d / split;
    int c0 = zb * NB;
    float* S = Spart + (size_t)z * NB * NB;
    __shared__ float As[BK][64];
    __shared__ float Bs[BK][64];
    int tid = threadIdx.x;
    int i0 = blockIdx.y * 64, j0 = blockIdx.x * 64;
    int tm = (tid >> 4) * 8, tn = (tid & 15) * 4;
    int sk = tid >> 4;
    int sc = (tid & 15) * 4;
    float acc[8][4] = {};
    int kb = ks * chunk, ke = kb + chunk;
    for (int k0 = kb; k0 < ke; k0 += BK) {
        #pragma unroll
        for (int p = 0; p < 2; ++p) {
            int kk = sk + p * 8;
            *(float4*)&As[kk][sc] = *(const float4*)(A + (size_t)(k0 + kk) * d + c0 + i0 + sc);
            *(float4*)&Bs[kk][sc] = *(const float4*)(A + (size_t)(k0 + kk) * d + c0 + j0 + sc);
        }
        __syncthreads();
        #pragma unroll
        for (int k = 0; k < BK; ++k) {
            float4 alo = *(const float4*)&As[k][tm];
            float4 ahi = *(const float4*)&As[k][tm + 4];
            float4 bv  = *(const float4*)&Bs[k][tn];
            float a[8] = {alo.x, alo.y, alo.z, alo.w, ahi.x, ahi.y, ahi.z, ahi.w};
            float b[4] = {bv.x, bv.y, bv.z, bv.w};
            #pragma unroll
            for (int i = 0; i < 8; ++i)
                #pragma unroll
                for (int j = 0; j < 4; ++j) acc[i][j] = fmaf(a[i], b[j], acc[i][j]);
        }
        __syncthreads();
    }
    #pragma unroll
    for (int i = 0; i < 8; ++i) {
        float4 v = make_float4(acc[i][0], acc[i][1], acc[i][2], acc[i][3]);
        *(float4*)(S + (size_t)(i0 + tm + i) * NB + j0 + tn) = v;
    }
}

// S[b] = sum_s Spart[b*split + s]
__global__ __launch_bounds__(256) void reduce_S(const float* __restrict__ src, float* __restrict__ dst, int split) {
    int b = blockIdx.y;
    int i = blockIdx.x * 256 + threadIdx.x;
    const float* p = src + (size_t)b * split * NB * NB + i;
    float acc = 0.0f;
    for (int s = 0; s < split; ++s) acc += p[(size_t)s * NB * NB];
    dst[(size_t)b * NB * NB + i] = acc;
}

// ---------------- M = D T D, T = (0.5 I + triu(D S D, 1))^{-1}; register-resident ----------------
__global__ __launch_bounds__(64) void trinv_scaled(const float* __restrict__ Sall, float* __restrict__ Mall,
                                                   const float* __restrict__ n2u, const float* __restrict__ n2v) {
    int j = blockIdx.x;
    int b = blockIdx.y;
    const float* S = Sall + (size_t)b * NB * NB;
    float* M = Mall + (size_t)b * NB * NB;
    const float* n2 = (b < 4) ? (n2u + b * NB) : (n2v + (size_t)(b - 4) * NB);
    int l = threadIdx.x;
    float in0 = 1.0f / sqrtf(n2[l]);
    float in1 = 1.0f / sqrtf(n2[l + 64]);
    float in2 = 1.0f / sqrtf(n2[l + 128]);
    float in3 = 1.0f / sqrtf(n2[l + 192]);
    float invnj = 1.0f / sqrtf(n2[j]);
    float i20 = in0 * in0, i21 = in1 * in1, i22 = in2 * in2, i23 = in3 * in3;
    float x0 = 0, x1 = 0, x2 = 0, x3 = 0;
    float a0 = 0, a1 = 0, a2 = 0, a3 = 0;
    int jq = j >> 6, jr = j & 63;
    if (l == jr) {
        float yj = 2.0f * invnj;
        if (jq == 0) x0 = yj; else if (jq == 1) x1 = yj; else if (jq == 2) x2 = yj; else x3 = yj;
    }
    float s0 = 0, s1 = 0, s2 = 0, s3 = 0;
    if (j >= 1) {
        const float* Sr = S + (size_t)j * NB;
        s0 = Sr[l]; s1 = Sr[l + 64]; s2 = Sr[l + 128]; s3 = Sr[l + 192];
    }
    for (int k = j; k >= 1; --k) {
        int kq = k >> 6, kr = k & 63;
        float yk;
        if      (kq == 0) yk = __shfl(x0, kr);
        else if (kq == 1) yk = __shfl(x1, kr);
        else if (kq == 2) yk = __shfl(x2, kr);
        else              yk = __shfl(x3, kr);
        float c0 = s0, c1 = s1, c2 = s2, c3 = s3;
        if (k > 1) {
            const float* Sn = S + (size_t)(k - 1) * NB;
            s0 = Sn[l]; s1 = Sn[l + 64]; s2 = Sn[l + 128]; s3 = Sn[l + 192];
        }
        a0 = fmaf(c0, yk, a0);
        a1 = fmaf(c1, yk, a1);
        a2 = fmaf(c2, yk, a2);
        a3 = fmaf(c3, yk, a3);
        int i = k - 1, iq = i >> 6, ir = i & 63;
        if (l == ir) {
            if      (iq == 0) x0 = -2.0f * i20 * a0;
            else if (iq == 1) x1 = -2.0f * i21 * a1;
            else if (iq == 2) x2 = -2.0f * i22 * a2;
            else              x3 = -2.0f * i23 * a3;
        }
    }
    M[(size_t)(l      ) * NB + j] = x0 * invnj;
    M[(size_t)(l +  64) * NB + j] = x1 * invnj;
    M[(size_t)(l + 128) * NB + j] = x2 * invnj;
    M[(size_t)(l + 192) * NB + j] = x3 * invnj;
}

// ---------------- TB_z = M_z @ B_z^T  (nt, K=NB, batched over z) ----------------
__global__ __launch_bounds__(128) void gemm128_nt_batch(const float* __restrict__ Aall,
                                                        const float* __restrict__ Bsrc, int d,
                                                        float* __restrict__ Call) {
    int z = blockIdx.z;
    const float* A = Aall + (size_t)z * NB * NB;
    const float* B = Bsrc + (size_t)z * NB;
    float* C = Call + (size_t)z * NB * d;
    int m0 = blockIdx.y * 64, n0 = blockIdx.x * 64;
    __shared__ float As[BK][64];
    __shared__ float Bs[BK][64];
    int tid = threadIdx.x;
    int tm = (tid >> 4) * 8, tn = (tid & 15) * 4;
    int ar = tid >> 2;
    int ac = (tid & 3) * 4;
    float acc[8][4] = {};
    for (int k0 = 0; k0 < NB; k0 += BK) {
        #pragma unroll
        for (int p = 0; p < 2; ++p) {
            int r = ar + p * 32;
            float4 av = *(const float4*)(A + (size_t)(m0 + r) * NB + k0 + ac);
            As[ac + 0][r] = av.x; As[ac + 1][r] = av.y; As[ac + 2][r] = av.z; As[ac + 3][r] = av.w;
            float4 bv = *(const float4*)(B + (size_t)(n0 + r) * d + k0 + ac);
            Bs[ac + 0][r] = bv.x; Bs[ac + 1][r] = bv.y; Bs[ac + 2][r] = bv.z; Bs[ac + 3][r] = bv.w;
        }
        __syncthreads();
        #pragma unroll
        for (int k = 0; k < BK; ++k) {
            float4 alo = *(const float4*)&As[k][tm];
            float4 ahi = *(const float4*)&As[k][tm + 4];
            float4 bv  = *(const float4*)&Bs[k][tn];
            float a[8] = {alo.x, alo.y, alo.z, alo.w, ahi.x, ahi.y, ahi.z, ahi.w};
            float b[4] = {bv.x, bv.y, bv.z, bv.w};
            #pragma unroll
            for (int i = 0; i < 8; ++i)
                #pragma unroll
                for (int j = 0; j < 4; ++j) acc[i][j] = fmaf(a[i], b[j], acc[i][j]);
        }
        __syncthreads();
    }
    #pragma unroll
    for (int i = 0; i < 8; ++i) {
        float4 v = make_float4(acc[i][0], acc[i][1], acc[i][2], acc[i][3]);
        *(float4*)(C + (size_t)(m0 + tm + i) * d + n0 + tn) = v;
    }
}

// ---------------- P0parts[z] = W @ Bblk over K-chunk z (plain store, no atomics) ----------------
__global__ __launch_bounds__(128) void gemm_part(const float* __restrict__ A, int ldA,
                                                 const float* __restrict__ B, int ldB,
                                                 float* __restrict__ Cparts, int kchunk) {
    int z = blockIdx.z;
    float* C = Cparts + (size_t)z * CI * NB;
    int m0 = blockIdx.y * 64, n0 = blockIdx.x * 64;
    int kb = z * kchunk, ke = kb + kchunk;
    __shared__ float As[BK][64];
    __shared__ float Bs[BK][64];
    int tid = threadIdx.x;
    int tm = (tid >> 4) * 8, tn = (tid & 15) * 4;
    int ar = tid >> 2;
    int ac = (tid & 3) * 4;
    int bk = tid >> 4;
    int bn = (tid & 15) * 4;
    float acc[8][4] = {};
    for (int k0 = kb; k0 < ke; k0 += BK) {
        #pragma unroll
        for (int p = 0; p < 2; ++p) {
            int r = ar + p * 32;
            float4 av = *(const float4*)(A + (size_t)(m0 + r) * ldA + k0 + ac);
            As[ac + 0][r] = av.x; As[ac + 1][r] = av.y; As[ac + 2][r] = av.z; As[ac + 3][r] = av.w;
        }
        #pragma unroll
        for (int p = 0; p < 2; ++p) {
            int kk = bk + p * 8;
            *(float4*)&Bs[kk][bn] = *(const float4*)(B + (size_t)(k0 + kk) * ldB + n0 + bn);
        }
        __syncthreads();
        #pragma unroll
        for (int k = 0; k < BK; ++k) {
            float4 alo = *(const float4*)&As[k][tm];
            float4 ahi = *(const float4*)&As[k][tm + 4];
            float4 bv  = *(const float4*)&Bs[k][tn];
            float a[8] = {alo.x, alo.y, alo.z, alo.w, ahi.x, ahi.y, ahi.z, ahi.w};
            float b[4] = {bv.x, bv.y, bv.z, bv.w};
            #pragma unroll
            for (int i = 0; i < 8; ++i)
                #pragma unroll
                for (int j = 0; j < 4; ++j) acc[i][j] = fmaf(a[i], b[j], acc[i][j]);
        }
        __syncthreads();
    }
    #pragma unroll
    for (int i = 0; i < 8; ++i) {
        float4 v = make_float4(acc[i][0], acc[i][1], acc[i][2], acc[i][3]);
        *(float4*)(C + (size_t)(m0 + tm + i) * NB + n0 + tn) = v;
    }
}

// ---------------- W -= (sum_s Apart[s]) @ B   (A: 1024xNB, B: NB x d, C=W ld CO) ----------------
template<int NPART>
__global__ __launch_bounds__(128) void gemm_sub_fused(const float* __restrict__ A, int ldA, size_t partStride,
                                                      const float* __restrict__ B, int ldB,
                                                      float* __restrict__ C) {
    int m0 = blockIdx.y * 64, n0 = blockIdx.x * 64;
    __shared__ float As[BK][64];
    __shared__ float Bs[BK][64];
    int tid = threadIdx.x;
    int tm = (tid >> 4) * 8, tn = (tid & 15) * 4;
    int ar = tid >> 2;
    int ac = (tid & 3) * 4;
    int bk = tid >> 4;
    int bn = (tid & 15) * 4;
    float acc[8][4] = {};
    for (int k0 = 0; k0 < NB; k0 += BK) {
        #pragma unroll
        for (int p = 0; p < 2; ++p) {
            int r = ar + p * 32;
            const float* ap = A + (size_t)(m0 + r) * ldA + k0 + ac;
            float4 av = *(const float4*)ap;
            #pragma unroll
            for (int s = 1; s < NPART; ++s) {
                float4 v = *(const float4*)(ap + (size_t)s * partStride);
                av.x += v.x; av.y += v.y; av.z += v.z; av.w += v.w;
            }
            As[ac + 0][r] = av.x; As[ac + 1][r] = av.y; As[ac + 2][r] = av.z; As[ac + 3][r] = av.w;
        }
        #pragma unroll
        for (int p = 0; p < 2; ++p) {
            int kk = bk + p * 8;
            *(float4*)&Bs[kk][bn] = *(const float4*)(B + (size_t)(k0 + kk) * ldB + n0 + bn);
        }
        __syncthreads();
        #pragma unroll
        for (int k = 0; k < BK; ++k) {
            float4 alo = *(const float4*)&As[k][tm];
            float4 ahi = *(const float4*)&As[k][tm + 4];
            float4 bv  = *(const float4*)&Bs[k][tn];
            float a[8] = {alo.x, alo.y, alo.z, alo.w, ahi.x, ahi.y, ahi.z, ahi.w};
            float b[4] = {bv.x, bv.y, bv.z, bv.w};
            #pragma unroll
            for (int i = 0; i < 8; ++i)
                #pragma unroll
                for (int j = 0; j < 4; ++j) acc[i][j] = fmaf(a[i], b[j], acc[i][j]);
        }
        __syncthreads();
    }
    #pragma unroll
    for (int i = 0; i < 8; ++i) {
        float* cp = C + (size_t)(m0 + tm + i) * CO + n0 + tn;
        float4 old = *(float4*)cp;
        old.x -= acc[i][0]; old.y -= acc[i][1]; old.z -= acc[i][2]; old.w -= acc[i][3];
        *(float4*)cp = old;
    }
}

extern "C" void kernel_launch(void* const* d_in, const int* in_sizes, int n_in,
                              void* d_out, int out_size, void* d_ws, size_t ws_size,
                              hipStream_t stream) {
    const float* U = (const float*)d_in[0];   // 1024x1024
    const float* V = (const float*)d_in[1];   // 2048x2048
    float* W = (float*)d_out;                 // 1024x2048, evolving product

    char* ws = (char*)d_ws;
    float* P0p  = (float*)(ws);                          //  8 MB: 8 x (1024x256) split-K partials
    float* S    = (float*)(ws + ((size_t)8  << 20));     //  3 MB: 12 x 256^2 (4 U then 8 V)
    float* M    = (float*)(ws + ((size_t)11 << 20));     //  3 MB
    float* TBu  = (float*)(ws + ((size_t)14 << 20));     //  4 MB (4 x 256x1024)
    float* TBv  = (float*)(ws + ((size_t)18 << 20));     // 16 MB (8 x 256x2048)
    float* n2u  = (float*)(ws + ((size_t)34 << 20));     //  4 KB
    float* n2v  = n2u + CI;
    // Gram partials alias the TB region (consumed by reduce_S before TB is written)
    float* SpU  = TBu;                                   //  4 MB: 4 blk x 4 splits
    float* SpV  = TBv;                                   // 16 MB: 8 blk x 8 splits

    float* Su = S;  float* Sv = S + (size_t)4 * NB * NB;
    float* Mu = M;  float* Mv = M + (size_t)4 * NB * NB;

    // 1) raw column norms
    hipMemsetAsync(n2u, 0, (CI + CO) * sizeof(float), stream);
    colnorm2<<<dim3(CI / 256, CI / 64), dim3(256), 0, stream>>>(U, n2u, CI);
    colnorm2<<<dim3(CO / 256, CO / 64), dim3(256), 0, stream>>>(V, n2v, CO);

    // 2) Gram partials (no atomics) + reduce + scaled triangular inverse
    gram_part<<<dim3(NB / 64, NB / 64, (CI / NB) * 4), dim3(128), 0, stream>>>(U, CI, 4, SpU);
    gram_part<<<dim3(NB / 64, NB / 64, (CO / NB) * 8), dim3(128), 0, stream>>>(V, CO, 8, SpV);
    reduce_S<<<dim3(NB * NB / 256, CI / NB), dim3(256), 0, stream>>>(SpU, Su, 4);
    reduce_S<<<dim3(NB * NB / 256, CO / NB), dim3(256), 0, stream>>>(SpV, Sv, 8);
    trinv_scaled<<<dim3(NB, 12), dim3(64), 0, stream>>>(S, M, n2u, n2v);

    // 3) TB_i = M_i @ B_i^T  (overwrites the Spart alias — already consumed)
    gemm128_nt_batch<<<dim3(CI / 64, NB / 64, CI / NB), dim3(128), 0, stream>>>(Mu, U, CI, TBu);
    gemm128_nt_batch<<<dim3(CO / 64, NB / 64, CO / NB), dim3(128), 0, stream>>>(Mv, V, CO, TBv);

    // 4) W = [I | 0]
    init_W<<<dim3(CO / 256, CI), dim3(256), 0, stream>>>(W);

    // 5) U-phase: W[:, :1024] -= (W[:, :1024] B_i) TB_i
    //    ib = 0 shortcut: W = [I|0]  =>  W B_0 = U[:, 0:256]  (single fused dispatch)
    gemm_sub_fused<1><<<dim3(CI / 64, CI / 64), dim3(128), 0, stream>>>(U, CI, 0, TBu, CI, W);
    for (int ib = 1; ib < CI / NB; ++ib) {
        gemm_part<<<dim3(NB / 64, CI / 64, 4), dim3(128), 0, stream>>>(W, CO, U + ib * NB, CI, P0p, CI / 4);
        gemm_sub_fused<4><<<dim3(CI / 64, CI / 64), dim3(128), 0, stream>>>(
            P0p, NB, (size_t)CI * NB, TBu + (size_t)ib * NB * CI, CI, W);
    }
    // 6) V-phase: W -= (W B_i) TB_i, full 2048 columns
    for (int ib = 0; ib < CO / NB; ++ib) {
        gemm_part<<<dim3(NB / 64, CI / 64, 8), dim3(128), 0, stream>>>(W, CO, V + ib * NB, CO, P0p, CO / 8);
        gemm_sub_fused<8><<<dim3(CO / 64, CI / 64), dim3(128), 0, stream>>>(
            P0p, NB, (size_t)CI * NB, TBv + (size_t)ib * NB * CO, CO, W);
    }
}

// Round 5
// 702.643 us; speedup vs baseline: 2.8357x; 1.8850x over previous
//
#include <hip/hip_runtime.h>
#include <hip/hip_bf16.h>
#include <cstdint>

// U: 1024x1024, V: 2048x2048, out = Qu @ Qv[:1024,:]  (f32 1024x2048)
#define CI 1024
#define CO 2048
#define NB 256   // WY block size
#define BK 16    // GEMM K-tile
#define TM 32    // chain-GEMM tile rows
#define TN 64    // chain-GEMM tile cols

// ---------------- utility ----------------

__global__ __launch_bounds__(256) void colnorm2(const float* __restrict__ M, float* __restrict__ n2, int d) {
    int c = blockIdx.x * 256 + threadIdx.x;
    int r0 = blockIdx.y * 64;
    float s = 0.0f;
    for (int r = r0; r < r0 + 64; ++r) {
        float v = M[(size_t)r * d + c];
        s = fmaf(v, v, s);
    }
    atomicAdd(&n2[c], s);
}

// W = [I | 0]   (1024 x 2048)
__global__ __launch_bounds__(256) void init_W(float* __restrict__ W) {
    int c = blockIdx.x * 256 + threadIdx.x;
    int r = blockIdx.y;
    W[(size_t)r * CO + c] = (c == r) ? 1.0f : 0.0f;
}

// ---------------- Gram partials: Spart[z] = A[:,zb]^T A[:,zb] over K-chunk ks ----------------
__global__ __launch_bounds__(128) void gram_part(const float* __restrict__ A, int d, int split,
                                                 float* __restrict__ Spart) {
    int z = blockIdx.z;
    int zb = z / split, ks = z % split;
    int chunk = d / split;
    int c0 = zb * NB;
    float* S = Spart + (size_t)z * NB * NB;
    __shared__ float As[BK][64];
    __shared__ float Bs[BK][64];
    int tid = threadIdx.x;
    int i0 = blockIdx.y * 64, j0 = blockIdx.x * 64;
    int tm = (tid >> 4) * 8, tn = (tid & 15) * 4;
    int sk = tid >> 4;
    int sc = (tid & 15) * 4;
    float acc[8][4] = {};
    int kb = ks * chunk, ke = kb + chunk;
    for (int k0 = kb; k0 < ke; k0 += BK) {
        #pragma unroll
        for (int p = 0; p < 2; ++p) {
            int kk = sk + p * 8;
            *(float4*)&As[kk][sc] = *(const float4*)(A + (size_t)(k0 + kk) * d + c0 + i0 + sc);
            *(float4*)&Bs[kk][sc] = *(const float4*)(A + (size_t)(k0 + kk) * d + c0 + j0 + sc);
        }
        __syncthreads();
        #pragma unroll
        for (int k = 0; k < BK; ++k) {
            float4 alo = *(const float4*)&As[k][tm];
            float4 ahi = *(const float4*)&As[k][tm + 4];
            float4 bv  = *(const float4*)&Bs[k][tn];
            float a[8] = {alo.x, alo.y, alo.z, alo.w, ahi.x, ahi.y, ahi.z, ahi.w};
            float b[4] = {bv.x, bv.y, bv.z, bv.w};
            #pragma unroll
            for (int i = 0; i < 8; ++i)
                #pragma unroll
                for (int j = 0; j < 4; ++j) acc[i][j] = fmaf(a[i], b[j], acc[i][j]);
        }
        __syncthreads();
    }
    #pragma unroll
    for (int i = 0; i < 8; ++i) {
        float4 v = make_float4(acc[i][0], acc[i][1], acc[i][2], acc[i][3]);
        *(float4*)(S + (size_t)(i0 + tm + i) * NB + j0 + tn) = v;
    }
}

// S[b] = sum_s Spart[b*split + s]
__global__ __launch_bounds__(256) void reduce_S(const float* __restrict__ src, float* __restrict__ dst, int split) {
    int b = blockIdx.y;
    int i = blockIdx.x * 256 + threadIdx.x;
    const float* p = src + (size_t)b * split * NB * NB + i;
    float acc = 0.0f;
    for (int s = 0; s < split; ++s) acc += p[(size_t)s * NB * NB];
    dst[(size_t)b * NB * NB + i] = acc;
}

// ---------------- M = D T D, T = (0.5 I + triu(D S D, 1))^{-1}; register-resident ----------------
__global__ __launch_bounds__(64) void trinv_scaled(const float* __restrict__ Sall, float* __restrict__ Mall,
                                                   const float* __restrict__ n2u, const float* __restrict__ n2v) {
    int j = blockIdx.x;
    int b = blockIdx.y;
    const float* S = Sall + (size_t)b * NB * NB;
    float* M = Mall + (size_t)b * NB * NB;
    const float* n2 = (b < 4) ? (n2u + b * NB) : (n2v + (size_t)(b - 4) * NB);
    int l = threadIdx.x;
    float in0 = 1.0f / sqrtf(n2[l]);
    float in1 = 1.0f / sqrtf(n2[l + 64]);
    float in2 = 1.0f / sqrtf(n2[l + 128]);
    float in3 = 1.0f / sqrtf(n2[l + 192]);
    float invnj = 1.0f / sqrtf(n2[j]);
    float i20 = in0 * in0, i21 = in1 * in1, i22 = in2 * in2, i23 = in3 * in3;
    float x0 = 0, x1 = 0, x2 = 0, x3 = 0;
    float a0 = 0, a1 = 0, a2 = 0, a3 = 0;
    int jq = j >> 6, jr = j & 63;
    if (l == jr) {
        float yj = 2.0f * invnj;
        if (jq == 0) x0 = yj; else if (jq == 1) x1 = yj; else if (jq == 2) x2 = yj; else x3 = yj;
    }
    float s0 = 0, s1 = 0, s2 = 0, s3 = 0;
    if (j >= 1) {
        const float* Sr = S + (size_t)j * NB;
        s0 = Sr[l]; s1 = Sr[l + 64]; s2 = Sr[l + 128]; s3 = Sr[l + 192];
    }
    for (int k = j; k >= 1; --k) {
        int kq = k >> 6, kr = k & 63;
        float yk;
        if      (kq == 0) yk = __shfl(x0, kr);
        else if (kq == 1) yk = __shfl(x1, kr);
        else if (kq == 2) yk = __shfl(x2, kr);
        else              yk = __shfl(x3, kr);
        float c0 = s0, c1 = s1, c2 = s2, c3 = s3;
        if (k > 1) {
            const float* Sn = S + (size_t)(k - 1) * NB;
            s0 = Sn[l]; s1 = Sn[l + 64]; s2 = Sn[l + 128]; s3 = Sn[l + 192];
        }
        a0 = fmaf(c0, yk, a0);
        a1 = fmaf(c1, yk, a1);
        a2 = fmaf(c2, yk, a2);
        a3 = fmaf(c3, yk, a3);
        int i = k - 1, iq = i >> 6, ir = i & 63;
        if (l == ir) {
            if      (iq == 0) x0 = -2.0f * i20 * a0;
            else if (iq == 1) x1 = -2.0f * i21 * a1;
            else if (iq == 2) x2 = -2.0f * i22 * a2;
            else              x3 = -2.0f * i23 * a3;
        }
    }
    M[(size_t)(l      ) * NB + j] = x0 * invnj;
    M[(size_t)(l +  64) * NB + j] = x1 * invnj;
    M[(size_t)(l + 128) * NB + j] = x2 * invnj;
    M[(size_t)(l + 192) * NB + j] = x3 * invnj;
}

// ---------------- TB_z = M_z @ B_z^T  (nt, K=NB, batched over z) ----------------
__global__ __launch_bounds__(128) void gemm128_nt_batch(const float* __restrict__ Aall,
                                                        const float* __restrict__ Bsrc, int d,
                                                        float* __restrict__ Call) {
    int z = blockIdx.z;
    const float* A = Aall + (size_t)z * NB * NB;
    const float* B = Bsrc + (size_t)z * NB;
    float* C = Call + (size_t)z * NB * d;
    int m0 = blockIdx.y * 64, n0 = blockIdx.x * 64;
    __shared__ float As[BK][64];
    __shared__ float Bs[BK][64];
    int tid = threadIdx.x;
    int tm = (tid >> 4) * 8, tn = (tid & 15) * 4;
    int ar = tid >> 2;
    int ac = (tid & 3) * 4;
    float acc[8][4] = {};
    for (int k0 = 0; k0 < NB; k0 += BK) {
        #pragma unroll
        for (int p = 0; p < 2; ++p) {
            int r = ar + p * 32;
            float4 av = *(const float4*)(A + (size_t)(m0 + r) * NB + k0 + ac);
            As[ac + 0][r] = av.x; As[ac + 1][r] = av.y; As[ac + 2][r] = av.z; As[ac + 3][r] = av.w;
            float4 bv = *(const float4*)(B + (size_t)(n0 + r) * d + k0 + ac);
            Bs[ac + 0][r] = bv.x; Bs[ac + 1][r] = bv.y; Bs[ac + 2][r] = bv.z; Bs[ac + 3][r] = bv.w;
        }
        __syncthreads();
        #pragma unroll
        for (int k = 0; k < BK; ++k) {
            float4 alo = *(const float4*)&As[k][tm];
            float4 ahi = *(const float4*)&As[k][tm + 4];
            float4 bv  = *(const float4*)&Bs[k][tn];
            float a[8] = {alo.x, alo.y, alo.z, alo.w, ahi.x, ahi.y, ahi.z, ahi.w};
            float b[4] = {bv.x, bv.y, bv.z, bv.w};
            #pragma unroll
            for (int i = 0; i < 8; ++i)
                #pragma unroll
                for (int j = 0; j < 4; ++j) acc[i][j] = fmaf(a[i], b[j], acc[i][j]);
        }
        __syncthreads();
    }
    #pragma unroll
    for (int i = 0; i < 8; ++i) {
        float4 v = make_float4(acc[i][0], acc[i][1], acc[i][2], acc[i][3]);
        *(float4*)(C + (size_t)(m0 + tm + i) * d + n0 + tn) = v;
    }
}

// ---------------- chain GEMM 1: P0parts[z] = W @ Bblk over K-chunk z  (TMxTN, dbuf) ----------------
__global__ __launch_bounds__(128) void chain_part(const float* __restrict__ A, int ldA,
                                                  const float* __restrict__ B, int ldB,
                                                  float* __restrict__ Cparts, int kchunk) {
    int z = blockIdx.z;
    float* C = Cparts + (size_t)z * CI * NB;
    int m0 = blockIdx.y * TM, n0 = blockIdx.x * TN;
    int kb = z * kchunk;
    __shared__ float As[2][BK][TM];
    __shared__ float Bs[2][BK][TN];
    int tid = threadIdx.x;
    int tm = (tid >> 4) * 4, tn = (tid & 15) * 4;
    int ar = tid >> 2, ac = (tid & 3) * 4;      // A stage: row 0..31, k {0,4,8,12}
    int bk = tid >> 4, bn = (tid & 15) * 4;     // B stage: k 0..7 (+8)
    float acc[4][4] = {};
    const float* Ap = A + (size_t)(m0 + ar) * ldA + ac;
    float4 av  = *(const float4*)(Ap + kb);
    float4 bv0 = *(const float4*)(B + (size_t)(kb + bk) * ldB + n0 + bn);
    float4 bv1 = *(const float4*)(B + (size_t)(kb + bk + 8) * ldB + n0 + bn);
    As[0][ac + 0][ar] = av.x; As[0][ac + 1][ar] = av.y; As[0][ac + 2][ar] = av.z; As[0][ac + 3][ar] = av.w;
    *(float4*)&Bs[0][bk][bn] = bv0;
    *(float4*)&Bs[0][bk + 8][bn] = bv1;
    __syncthreads();
    int nt = kchunk / BK;
    for (int t = 0; t < nt; ++t) {
        int cur = t & 1;
        if (t + 1 < nt) {
            int k0 = kb + (t + 1) * BK;
            av  = *(const float4*)(Ap + k0);
            bv0 = *(const float4*)(B + (size_t)(k0 + bk) * ldB + n0 + bn);
            bv1 = *(const float4*)(B + (size_t)(k0 + bk + 8) * ldB + n0 + bn);
        }
        #pragma unroll
        for (int k = 0; k < BK; ++k) {
            float4 a = *(const float4*)&As[cur][k][tm];
            float4 b = *(const float4*)&Bs[cur][k][tn];
            float aa[4] = {a.x, a.y, a.z, a.w};
            float bb[4] = {b.x, b.y, b.z, b.w};
            #pragma unroll
            for (int i = 0; i < 4; ++i)
                #pragma unroll
                for (int j = 0; j < 4; ++j) acc[i][j] = fmaf(aa[i], bb[j], acc[i][j]);
        }
        if (t + 1 < nt) {
            int nxt = cur ^ 1;
            As[nxt][ac + 0][ar] = av.x; As[nxt][ac + 1][ar] = av.y;
            As[nxt][ac + 2][ar] = av.z; As[nxt][ac + 3][ar] = av.w;
            *(float4*)&Bs[nxt][bk][bn] = bv0;
            *(float4*)&Bs[nxt][bk + 8][bn] = bv1;
            __syncthreads();
        }
    }
    #pragma unroll
    for (int i = 0; i < 4; ++i) {
        float4 v = make_float4(acc[i][0], acc[i][1], acc[i][2], acc[i][3]);
        *(float4*)(C + (size_t)(m0 + tm + i) * NB + n0 + tn) = v;
    }
}

// ---------------- chain GEMM 2: W -= (sum_s Apart[s]) @ B  (TMxTN, dbuf, K=NB) ----------------
template<int NPART>
__global__ __launch_bounds__(128) void chain_sub_fused(const float* __restrict__ A, int ldA, size_t partStride,
                                                       const float* __restrict__ B, int ldB,
                                                       float* __restrict__ C) {
    int m0 = blockIdx.y * TM, n0 = blockIdx.x * TN;
    __shared__ float As[2][BK][TM];
    __shared__ float Bs[2][BK][TN];
    int tid = threadIdx.x;
    int tm = (tid >> 4) * 4, tn = (tid & 15) * 4;
    int ar = tid >> 2, ac = (tid & 3) * 4;
    int bk = tid >> 4, bn = (tid & 15) * 4;
    float acc[4][4] = {};
    const float* Ap = A + (size_t)(m0 + ar) * ldA + ac;
    float4 av, bv0, bv1;
    {
        av = *(const float4*)(Ap);
        #pragma unroll
        for (int s = 1; s < NPART; ++s) {
            float4 v = *(const float4*)(Ap + (size_t)s * partStride);
            av.x += v.x; av.y += v.y; av.z += v.z; av.w += v.w;
        }
        bv0 = *(const float4*)(B + (size_t)(bk) * ldB + n0 + bn);
        bv1 = *(const float4*)(B + (size_t)(bk + 8) * ldB + n0 + bn);
    }
    As[0][ac + 0][ar] = av.x; As[0][ac + 1][ar] = av.y; As[0][ac + 2][ar] = av.z; As[0][ac + 3][ar] = av.w;
    *(float4*)&Bs[0][bk][bn] = bv0;
    *(float4*)&Bs[0][bk + 8][bn] = bv1;
    __syncthreads();
    const int nt = NB / BK;
    for (int t = 0; t < nt; ++t) {
        int cur = t & 1;
        if (t + 1 < nt) {
            int k0 = (t + 1) * BK;
            av = *(const float4*)(Ap + k0);
            #pragma unroll
            for (int s = 1; s < NPART; ++s) {
                float4 v = *(const float4*)(Ap + k0 + (size_t)s * partStride);
                av.x += v.x; av.y += v.y; av.z += v.z; av.w += v.w;
            }
            bv0 = *(const float4*)(B + (size_t)(k0 + bk) * ldB + n0 + bn);
            bv1 = *(const float4*)(B + (size_t)(k0 + bk + 8) * ldB + n0 + bn);
        }
        #pragma unroll
        for (int k = 0; k < BK; ++k) {
            float4 a = *(const float4*)&As[cur][k][tm];
            float4 b = *(const float4*)&Bs[cur][k][tn];
            float aa[4] = {a.x, a.y, a.z, a.w};
            float bb[4] = {b.x, b.y, b.z, b.w};
            #pragma unroll
            for (int i = 0; i < 4; ++i)
                #pragma unroll
                for (int j = 0; j < 4; ++j) acc[i][j] = fmaf(aa[i], bb[j], acc[i][j]);
        }
        if (t + 1 < nt) {
            int nxt = cur ^ 1;
            As[nxt][ac + 0][ar] = av.x; As[nxt][ac + 1][ar] = av.y;
            As[nxt][ac + 2][ar] = av.z; As[nxt][ac + 3][ar] = av.w;
            *(float4*)&Bs[nxt][bk][bn] = bv0;
            *(float4*)&Bs[nxt][bk + 8][bn] = bv1;
            __syncthreads();
        }
    }
    #pragma unroll
    for (int i = 0; i < 4; ++i) {
        float* cp = C + (size_t)(m0 + tm + i) * CO + n0 + tn;
        float4 old = *(float4*)cp;
        old.x -= acc[i][0]; old.y -= acc[i][1]; old.z -= acc[i][2]; old.w -= acc[i][3];
        *(float4*)cp = old;
    }
}

extern "C" void kernel_launch(void* const* d_in, const int* in_sizes, int n_in,
                              void* d_out, int out_size, void* d_ws, size_t ws_size,
                              hipStream_t stream) {
    const float* U = (const float*)d_in[0];   // 1024x1024
    const float* V = (const float*)d_in[1];   // 2048x2048
    float* W = (float*)d_out;                 // 1024x2048, evolving product

    char* ws = (char*)d_ws;
    float* P0p  = (float*)(ws);                          //  8 MB: 8 x (1024x256) split-K partials
    float* S    = (float*)(ws + ((size_t)8  << 20));     //  3 MB: 12 x 256^2 (4 U then 8 V)
    float* M    = (float*)(ws + ((size_t)11 << 20));     //  3 MB
    float* TBu  = (float*)(ws + ((size_t)14 << 20));     //  4 MB (4 x 256x1024)
    float* TBv  = (float*)(ws + ((size_t)18 << 20));     // 16 MB (8 x 256x2048)
    float* n2u  = (float*)(ws + ((size_t)34 << 20));     //  4 KB
    float* n2v  = n2u + CI;
    // Gram partials alias the TB region (consumed by reduce_S before TB is written)
    float* SpU  = TBu;                                   //  4 MB: 4 blk x 4 splits
    float* SpV  = TBv;                                   // 16 MB: 8 blk x 8 splits

    float* Su = S;  float* Sv = S + (size_t)4 * NB * NB;
    float* Mu = M;  float* Mv = M + (size_t)4 * NB * NB;

    // 1) raw column norms
    hipMemsetAsync(n2u, 0, (CI + CO) * sizeof(float), stream);
    colnorm2<<<dim3(CI / 256, CI / 64), dim3(256), 0, stream>>>(U, n2u, CI);
    colnorm2<<<dim3(CO / 256, CO / 64), dim3(256), 0, stream>>>(V, n2v, CO);

    // 2) Gram partials (no atomics) + reduce + scaled triangular inverse
    gram_part<<<dim3(NB / 64, NB / 64, (CI / NB) * 4), dim3(128), 0, stream>>>(U, CI, 4, SpU);
    gram_part<<<dim3(NB / 64, NB / 64, (CO / NB) * 8), dim3(128), 0, stream>>>(V, CO, 8, SpV);
    reduce_S<<<dim3(NB * NB / 256, CI / NB), dim3(256), 0, stream>>>(SpU, Su, 4);
    reduce_S<<<dim3(NB * NB / 256, CO / NB), dim3(256), 0, stream>>>(SpV, Sv, 8);
    trinv_scaled<<<dim3(NB, 12), dim3(64), 0, stream>>>(S, M, n2u, n2v);

    // 3) TB_i = M_i @ B_i^T  (overwrites the Spart alias — already consumed)
    gemm128_nt_batch<<<dim3(CI / 64, NB / 64, CI / NB), dim3(128), 0, stream>>>(Mu, U, CI, TBu);
    gemm128_nt_batch<<<dim3(CO / 64, NB / 64, CO / NB), dim3(128), 0, stream>>>(Mv, V, CO, TBv);

    // 4) W = [I | 0]
    init_W<<<dim3(CO / 256, CI), dim3(256), 0, stream>>>(W);

    // 5) U-phase: W[:, :1024] -= (W[:, :1024] B_i) TB_i
    //    ib = 0 shortcut: W = [I|0]  =>  W B_0 = U[:, 0:256]  (single fused dispatch)
    chain_sub_fused<1><<<dim3(CI / TN, CI / TM), dim3(128), 0, stream>>>(U, CI, 0, TBu, CI, W);
    for (int ib = 1; ib < CI / NB; ++ib) {
        chain_part<<<dim3(NB / TN, CI / TM, 4), dim3(128), 0, stream>>>(W, CO, U + ib * NB, CI, P0p, CI / 4);
        chain_sub_fused<4><<<dim3(CI / TN, CI / TM), dim3(128), 0, stream>>>(
            P0p, NB, (size_t)CI * NB, TBu + (size_t)ib * NB * CI, CI, W);
    }
    // 6) V-phase: W -= (W B_i) TB_i, full 2048 columns
    for (int ib = 0; ib < CO / NB; ++ib) {
        chain_part<<<dim3(NB / TN, CI / TM, 8), dim3(128), 0, stream>>>(W, CO, V + ib * NB, CO, P0p, CO / 8);
        chain_sub_fused<8><<<dim3(CO / TN, CI / TM), dim3(128), 0, stream>>>(
            P0p, NB, (size_t)CI * NB, TBv + (size_t)ib * NB * CO, CO, W);
    }
}